// Round 1
// baseline (68.646 us; speedup 1.0000x reference)
//
#include <hip/hip_runtime.h>
#include <math.h>

#define TOKEN_NUMS 2004
#define PAD_IDX    2003
#define B_DIM      32
#define S_DIM      512
#define SP_DIM     510              // S - 2
#define NROWS      (B_DIM * SP_DIM) // 16320
#define ROW_F4     (TOKEN_NUMS / 4) // 501 float4s per row (2004*4=8016 bytes, 16B aligned stride)

// ---------------- Kernel 1: per-row argmax over 2004 classes ----------------
// One 64-lane wave per row. float4 vectorized loads, first-occurrence tie-break.
__global__ __launch_bounds__(256) void cvl_argmax_kernel(
    const float* __restrict__ pred, int* __restrict__ tok)
{
    int wid  = (int)((blockIdx.x * blockDim.x + threadIdx.x) >> 6); // wave id = row
    int lane = (int)(threadIdx.x & 63);
    if (wid >= NROWS) return;

    int b = wid / SP_DIM;
    int s = wid - b * SP_DIM;
    const float4* row = reinterpret_cast<const float4*>(
        pred + (size_t)(b * S_DIM + s) * TOKEN_NUMS);

    float best = -INFINITY;
    int   bidx = 0x7fffffff;
    #pragma unroll 4
    for (int j = lane; j < ROW_F4; j += 64) {
        float4 v = row[j];
        int base = j << 2;
        if (v.x > best) { best = v.x; bidx = base;     }
        if (v.y > best) { best = v.y; bidx = base + 1; }
        if (v.z > best) { best = v.z; bidx = base + 2; }
        if (v.w > best) { best = v.w; bidx = base + 3; }
    }
    // wave reduce: max value, ties -> lower index (jnp.argmax = first occurrence)
    #pragma unroll
    for (int off = 32; off >= 1; off >>= 1) {
        float ov = __shfl_xor(best, off);
        int   oi = __shfl_xor(bidx, off);
        if (ov > best || (ov == best && oi < bidx)) { best = ov; bidx = oi; }
    }
    if (lane == 0) tok[wid] = bidx;
}

// ---------------- Kernel 2: scan + detokenize + losses ----------------
// Single block, 256 threads, 64 consecutive tokens per thread (covers 16384 >= 16320).
__global__ __launch_bounds__(256) void cvl_loss_kernel(
    const int*   __restrict__ tok,
    const float* __restrict__ gt_acc,
    const float* __restrict__ gt_steer,
    const int*   __restrict__ gt_rev,
    float*       __restrict__ out)
{
    const int PER = 64;
    __shared__ int   s_cnt[256];
    __shared__ int   s_exc[257];
    __shared__ float s_red[256];

    int t     = (int)threadIdx.x;
    int start = t * PER;
    int end   = start + PER; if (end > NROWS) end = NROWS;
    if (start > NROWS) start = NROWS;

    // local valid-token count
    int lc = 0;
    for (int i = start; i < end; ++i) lc += (tok[i] != PAD_IDX) ? 1 : 0;
    s_cnt[t] = lc;
    __syncthreads();

    // exclusive scan (serial by thread 0 — 256 adds, negligible; order-exact)
    if (t == 0) {
        int run = 0;
        for (int i = 0; i < 256; ++i) { s_exc[i] = run; run += s_cnt[i]; }
        s_exc[256] = run;
    }
    __syncthreads();

    int   total = s_exc[256];
    float cnt   = fmaxf((float)total, 1.0f);
    const float lse   = log1pf(expf(1.0f));
    const float scale = 1.0f / 9.0f;   // 1/(BASE-1)

    float accAS = 0.0f;   // smooth_l1(acc) + smooth_l1(steer) partial sum
    float accR  = 0.0f;   // (lse - logit_at_gt) partial sum
    float ceC   = 0.0f;   // ce_mask partial count

    int run = s_exc[t];
    for (int i = start; i < end; ++i) {
        int tk = tok[i];
        if (tk == PAD_IDX) continue;     // fmask == 0 -> zero contribution
        run += 1;
        int pos = run - 1;               // cumsum(mask)-1, >=0 here

        int rev = tk & 1;
        int st  = (tk >> 1) % 10;
        int bt  = (tk / 20) % 10;
        int tt  = (tk / 200) % 10;

        float throttle = (float)tt * scale;
        float brake    = (float)bt * scale;
        float acc_p    = throttle - brake;
        float steer_p  = (float)st * scale * 2.0f - 1.0f;

        float d = acc_p - gt_acc[pos];
        float a = fabsf(d);
        accAS += (a < 1.0f) ? 0.5f * d * d : a - 0.5f;

        d = steer_p - gt_steer[pos];
        a = fabsf(d);
        accAS += (a < 1.0f) ? 0.5f * d * d : a - 0.5f;

        int g = gt_rev[pos];
        if (g != PAD_IDX) {
            float logit = (rev == g) ? 1.0f : 0.0f;
            accR += (lse - logit);
            ceC  += 1.0f;
        }
    }

    // block tree-reduce the three partials
    s_red[t] = accAS; __syncthreads();
    for (int o = 128; o >= 1; o >>= 1) {
        if (t < o) s_red[t] += s_red[t + o];
        __syncthreads();
    }
    float redAS = s_red[0]; __syncthreads();

    s_red[t] = accR; __syncthreads();
    for (int o = 128; o >= 1; o >>= 1) {
        if (t < o) s_red[t] += s_red[t + o];
        __syncthreads();
    }
    float redR = s_red[0]; __syncthreads();

    s_red[t] = ceC; __syncthreads();
    for (int o = 128; o >= 1; o >>= 1) {
        if (t < o) s_red[t] += s_red[t + o];
        __syncthreads();
    }
    float redCe = s_red[0];

    if (t == 0) {
        out[0] = redAS / cnt;                     // acc_val_loss + steer_val_loss
        out[1] = redR / fmaxf(redCe, 1.0f);       // reverse_val_loss
    }
}

extern "C" void kernel_launch(void* const* d_in, const int* in_sizes, int n_in,
                              void* d_out, int out_size, void* d_ws, size_t ws_size,
                              hipStream_t stream)
{
    const float* pred     = (const float*)d_in[0];
    const float* gt_acc   = (const float*)d_in[1];
    const float* gt_steer = (const float*)d_in[2];
    const int*   gt_rev   = (const int*)d_in[3];
    float*       out      = (float*)d_out;
    int*         tok      = (int*)d_ws;   // NROWS ints = 65280 B

    // one wave per row, 4 waves per block
    int blocks = (NROWS + 3) / 4;         // 4080
    hipLaunchKernelGGL(cvl_argmax_kernel, dim3(blocks), dim3(256), 0, stream, pred, tok);
    hipLaunchKernelGGL(cvl_loss_kernel, dim3(1), dim3(256), 0, stream,
                       tok, gt_acc, gt_steer, gt_rev, out);
}

// Round 2
// 45.176 us; speedup vs baseline: 1.5195x; 1.5195x over previous
//
#include <hip/hip_runtime.h>
#include <math.h>

#define TOKEN_NUMS 2004
#define PAD_IDX    2003
#define B_DIM      32
#define S_DIM      512
#define SP_DIM     510              // S - 2
#define NROWS      (B_DIM * SP_DIM) // 16320
#define NWAVES     (NROWS / 64)     // 255 chunks of 64 tokens
#define ROW_F4     (TOKEN_NUMS / 4) // 501 float4s per row

// ---------------- Kernel 1: per-row argmax over 2004 classes ----------------
// One 64-lane wave per row. 8 float4 loads issued up front (7 full + 1 tail),
// then compare chain; first-occurrence tie-break to match jnp.argmax.
__global__ __launch_bounds__(256) void cvl_argmax_kernel(
    const float* __restrict__ pred, int* __restrict__ tok)
{
    int wid  = (int)((blockIdx.x * blockDim.x + threadIdx.x) >> 6);
    int lane = (int)(threadIdx.x & 63);
    if (wid >= NROWS) return;

    int b = wid / SP_DIM;
    int s = wid - b * SP_DIM;
    const float4* row = reinterpret_cast<const float4*>(
        pred + (size_t)(b * S_DIM + s) * TOKEN_NUMS);

    // 501 = 7*64 + 53: 7 unconditional strided loads + 1 predicated tail.
    float4 v[8];
    #pragma unroll
    for (int k = 0; k < 7; ++k) v[k] = row[lane + 64 * k];
    bool tail = lane < (ROW_F4 - 7 * 64);   // lane < 53
    v[7] = tail ? row[lane + 7 * 64]
                : make_float4(-INFINITY, -INFINITY, -INFINITY, -INFINITY);

    float best = -INFINITY;
    int   bidx = 0x7fffffff;
    #pragma unroll
    for (int k = 0; k < 8; ++k) {
        int base = (lane + 64 * k) << 2;
        if (v[k].x > best) { best = v[k].x; bidx = base;     }
        if (v[k].y > best) { best = v[k].y; bidx = base + 1; }
        if (v[k].z > best) { best = v[k].z; bidx = base + 2; }
        if (v[k].w > best) { best = v[k].w; bidx = base + 3; }
    }
    // wave reduce: max value, ties -> lower index
    #pragma unroll
    for (int off = 32; off >= 1; off >>= 1) {
        float ov = __shfl_xor(best, off);
        int   oi = __shfl_xor(bidx, off);
        if (ov > best || (ov == best && oi < bidx)) { best = ov; bidx = oi; }
    }
    if (lane == 0) tok[wid] = bidx;
}

// ---------------- Kernel 2: ballot-scan + detokenize + losses ----------------
// Single block, 1024 threads = 16 waves. Wave-parallel via __ballot/popcll:
// no per-thread serial token loop anywhere.
__global__ __launch_bounds__(1024) void cvl_loss_kernel(
    const int*   __restrict__ tok,
    const float* __restrict__ gt_acc,
    const float* __restrict__ gt_steer,
    const int*   __restrict__ gt_rev,
    float*       __restrict__ out)
{
    __shared__ int   s_cnt[NWAVES];
    __shared__ int   s_base[NWAVES + 1];
    __shared__ float s_red[3][16];

    int tid  = (int)threadIdx.x;
    int wv   = tid >> 6;          // 0..15
    int lane = tid & 63;

    // Phase A: per-64-chunk valid counts via ballot (coalesced, L2-hot)
    for (int c = wv; c < NWAVES; c += 16) {
        int tk = tok[c * 64 + lane];
        unsigned long long m = __ballot(tk != PAD_IDX);
        if (lane == 0) s_cnt[c] = __popcll(m);
    }
    __syncthreads();

    // Phase B: serial exclusive scan of 255 counts (order-exact, ~255 adds)
    if (tid == 0) {
        int run = 0;
        for (int c = 0; c < NWAVES; ++c) { s_base[c] = run; run += s_cnt[c]; }
        s_base[NWAVES] = run;
    }
    __syncthreads();

    float cnt = fmaxf((float)s_base[NWAVES], 1.0f);
    const float lse   = log1pf(expf(1.0f));
    const float scale = 1.0f / 9.0f;   // 1/(BASE-1)

    float accAS = 0.0f, accR = 0.0f, ceC = 0.0f;

    // Phase C: pos = chunk base + intra-wave prefix popcount; gather + loss
    for (int c = wv; c < NWAVES; c += 16) {
        int i  = c * 64 + lane;
        int tk = tok[i];
        bool valid = (tk != PAD_IDX);
        unsigned long long m = __ballot(valid);
        if (valid) {
            int pos = s_base[c] + __popcll(m & ((1ull << lane) - 1ull));

            int rev = tk & 1;
            int st  = (tk >> 1) % 10;
            int bt  = (tk / 20) % 10;
            int tt  = (tk / 200) % 10;

            float acc_p   = (float)tt * scale - (float)bt * scale;
            float steer_p = (float)st * scale * 2.0f - 1.0f;

            float d = acc_p - gt_acc[pos];
            float a = fabsf(d);
            accAS += (a < 1.0f) ? 0.5f * d * d : a - 0.5f;

            d = steer_p - gt_steer[pos];
            a = fabsf(d);
            accAS += (a < 1.0f) ? 0.5f * d * d : a - 0.5f;

            int g = gt_rev[pos];
            if (g != PAD_IDX) {
                accR += lse - ((rev == g) ? 1.0f : 0.0f);
                ceC  += 1.0f;
            }
        }
    }

    // wave shuffle-reduce, then 16 partials via LDS
    #pragma unroll
    for (int o = 32; o >= 1; o >>= 1) {
        accAS += __shfl_down(accAS, o);
        accR  += __shfl_down(accR,  o);
        ceC   += __shfl_down(ceC,   o);
    }
    if (lane == 0) { s_red[0][wv] = accAS; s_red[1][wv] = accR; s_red[2][wv] = ceC; }
    __syncthreads();

    if (tid == 0) {
        float rAS = 0.0f, rR = 0.0f, rC = 0.0f;
        #pragma unroll
        for (int w = 0; w < 16; ++w) {
            rAS += s_red[0][w]; rR += s_red[1][w]; rC += s_red[2][w];
        }
        out[0] = rAS / cnt;
        out[1] = rR / fmaxf(rC, 1.0f);
    }
}

extern "C" void kernel_launch(void* const* d_in, const int* in_sizes, int n_in,
                              void* d_out, int out_size, void* d_ws, size_t ws_size,
                              hipStream_t stream)
{
    const float* pred     = (const float*)d_in[0];
    const float* gt_acc   = (const float*)d_in[1];
    const float* gt_steer = (const float*)d_in[2];
    const int*   gt_rev   = (const int*)d_in[3];
    float*       out      = (float*)d_out;
    int*         tok      = (int*)d_ws;   // NROWS ints = 65280 B

    int blocks = (NROWS + 3) / 4;         // 4 waves/block, one wave per row
    hipLaunchKernelGGL(cvl_argmax_kernel, dim3(blocks), dim3(256), 0, stream, pred, tok);
    hipLaunchKernelGGL(cvl_loss_kernel, dim3(1), dim3(1024), 0, stream,
                       tok, gt_acc, gt_steer, gt_rev, out);
}